// Round 12
// baseline (220.096 us; speedup 1.0000x reference)
//
#include <hip/hip_runtime.h>
#include <hip/hip_bf16.h>

// Problem: B=4, T=1024, C=1024, H=16, D=64, MAX_LEN=1024, NPOS=2047
// Pipeline (3 launches):
//   gemm_bt<0,f32A>: qkv = x @ qkv_w^T + b (cvt fused) -> scatter bf16
//                    (Q,K [t][d], V [d][t]); grid row y==24 folds table_reduce
//   attn_mfma: flash causal, 128-query blocks, 128-KEY staging pairs,
//              S^T-softmax, diagonal wave-skip -> y (B,T,C) bf16
//   gemm_bt<1,bf16A>: out = y @ proj_w^T + b -> fp32 d_out
//
// gemm_bt: EXACT R8 structure -- the measured plateau (61-65us, MfmaUtil 16%,
// occ 48%). Tried and rejected: R3 global_load_lds (77), R5 LDS dbuf (68),
// R7 dist-2 indexed regs (137, scratch spill), R9 BK=64 (78, occupancy cliff),
// R11 dist-2 named regs (75, VGPR 52 cut occupancy). DO NOT touch staging.
//
// attn R12: stage 128 keys per barrier-pair (was 64): barrier events per
// (b,h) 72 -> 36. LDS 58 KB -> 2 blocks/CU (= the 512-block average).
// Wave-uniform skip of fully-masked tile-halves at the diagonal.
//
// Workspace layout (bytes):
//   table@ 16777216  : 2047x16 f32     (128 KB)
//   qkvb @ 16908288  : (3,4,16,64K) bf16 (24 MB)
//   y    @ 42074112  : 4096x1024 bf16  (8 MB)

typedef __bf16 bf16x8 __attribute__((ext_vector_type(8)));
typedef float f32x4 __attribute__((ext_vector_type(4)));

__device__ __forceinline__ float bf2f(unsigned short u) {
    return __uint_as_float(((unsigned)u) << 16);
}
__device__ __forceinline__ unsigned short f2bf(float f) {
    __hip_bfloat16 h = __float2bfloat16(f);
    return *reinterpret_cast<unsigned short*>(&h);
}
__device__ __forceinline__ int4 cvt8(float4 a, float4 b) {
    union { unsigned short s[8]; int4 v; } u;
    u.s[0] = f2bf(a.x); u.s[1] = f2bf(a.y); u.s[2] = f2bf(a.z); u.s[3] = f2bf(a.w);
    u.s[4] = f2bf(b.x); u.s[5] = f2bf(b.y); u.s[6] = f2bf(b.z); u.s[7] = f2bf(b.w);
    return u.v;
}

// ---------------- bf16 MFMA GEMM: C = A B^T + bias (exact R8 body) ----------------
// 512 threads, 8 waves: wr=wave&1 (64-row half), wc=wave>>1 (32-col quarter).
// EPI=0: scatter bf16 into qkv planes; blockIdx.y==24 does table_reduce duty
// (rel (2047,1024) -> table (2047,16); two 256-thread groups, 64 p's/block).
// EPI=1: fp32 row-major out.
template <int EPI, bool AF32>
__global__ __launch_bounds__(512) void gemm_bt(const void* __restrict__ Ain,
                                               const float* __restrict__ Bf,
                                               const float* __restrict__ bias,
                                               unsigned short* __restrict__ outb,
                                               float* __restrict__ outf,
                                               const float* __restrict__ rel,
                                               float* __restrict__ table,
                                               int M, int N, int K) {
    const int tid = threadIdx.x;
    if (EPI == 0 && blockIdx.y == 24) {
        // table duty: group g = tid>>8 handles p = base + 2*it + g
        const int g = tid >> 8;
        const int t = tid & 255;
        const int lane = t & 63, wv = t >> 6;  // wv in 0..3
        for (int it = 0; it < 32; ++it) {
            const int p = blockIdx.x * 64 + it * 2 + g;
            if (p < 2047) {
                const float* r = rel + (size_t)p * 1024;
                float s0 = r[t], s1 = r[t + 256], s2 = r[t + 512], s3 = r[t + 768];
#pragma unroll
                for (int k = 0; k < 4; ++k) {
                    float v = (k == 0) ? s0 : (k == 1) ? s1 : (k == 2) ? s2 : s3;
                    for (int o = 32; o; o >>= 1) v += __shfl_xor(v, o, 64);
                    if (lane == 0) table[p * 16 + wv + 4 * k] = v;
                }
            }
        }
        return;
    }

    __shared__ __attribute__((aligned(16))) unsigned short As[128 * 40];
    __shared__ __attribute__((aligned(16))) unsigned short Bs[128 * 40];
    const int bm = blockIdx.x * 128, bn = blockIdx.y * 128;
    const int lane = tid & 63, wave = tid >> 6;
    const int wr = wave & 1, wc = wave >> 1;  // wc in 0..3
    const int quad = lane >> 4, lm = lane & 15;

    const int srow = tid >> 2;        // 0..127
    const int scol = (tid & 3) * 8;   // shorts / elements
    const float* ApF          = (const float*)Ain + (size_t)(bm + srow) * K + scol;
    const unsigned short* ApH = (const unsigned short*)Ain + (size_t)(bm + srow) * K + scol;
    const float* BpF          = Bf + (size_t)(bn + srow) * K + scol;
    unsigned short* AsW = &As[srow * 40 + scol];
    unsigned short* BsW = &Bs[srow * 40 + scol];

    f32x4 acc[4][2];
#pragma unroll
    for (int r = 0; r < 4; ++r)
#pragma unroll
        for (int c = 0; c < 2; ++c) acc[r][c] = (f32x4){0.f, 0.f, 0.f, 0.f};

    // prologue prefetch of tile 0 (named scalars -- no indexed reg arrays!)
    float4 paf0, paf1, pbf0, pbf1;
    int4 pah;
    if (AF32) {
        paf0 = *(const float4*)(ApF);
        paf1 = *(const float4*)(ApF + 4);
    } else {
        pah = *(const int4*)(ApH);
    }
    pbf0 = *(const float4*)(BpF);
    pbf1 = *(const float4*)(BpF + 4);

    for (int kk = 0; kk < K; kk += 32) {
        *(int4*)(AsW) = AF32 ? cvt8(paf0, paf1) : pah;
        *(int4*)(BsW) = cvt8(pbf0, pbf1);
        __syncthreads();

        if (kk + 32 < K) {
            if (AF32) {
                paf0 = *(const float4*)(ApF + kk + 32);
                paf1 = *(const float4*)(ApF + kk + 36);
            } else {
                pah = *(const int4*)(ApH + kk + 32);
            }
            pbf0 = *(const float4*)(BpF + kk + 32);
            pbf1 = *(const float4*)(BpF + kk + 36);
        }

        bf16x8 af[4], bfr[2];
#pragma unroll
        for (int r = 0; r < 4; ++r)
            af[r] = *(const bf16x8*)(&As[(64 * wr + 16 * r + lm) * 40 + quad * 8]);
#pragma unroll
        for (int c = 0; c < 2; ++c)
            bfr[c] = *(const bf16x8*)(&Bs[(32 * wc + 16 * c + lm) * 40 + quad * 8]);
#pragma unroll
        for (int r = 0; r < 4; ++r)
#pragma unroll
            for (int c = 0; c < 2; ++c)
                acc[r][c] = __builtin_amdgcn_mfma_f32_16x16x32_bf16(af[r], bfr[c], acc[r][c], 0, 0, 0);
        __syncthreads();
    }

    // C/D layout: col = lane&15, row = (lane>>4)*4 + reg
#pragma unroll
    for (int r = 0; r < 4; ++r)
#pragma unroll
        for (int c = 0; c < 2; ++c)
#pragma unroll
            for (int i = 0; i < 4; ++i) {
                const int row = bm + 64 * wr + 16 * r + quad * 4 + i;
                const int col = bn + 32 * wc + 16 * c + lm;
                const float v = acc[r][c][i] + bias[col];
                if (EPI == 0) {
                    const int b = row >> 10, t = row & 1023;
                    const int s3 = col >> 10, rem = col & 1023;
                    const int h = rem >> 6, d = rem & 63;
                    const size_t base = (((size_t)s3 * 4 + b) * 16 + h) * 65536;
                    const size_t off = base + (s3 == 2 ? (size_t)d * 1024 + t
                                                       : (size_t)t * 64 + d);
                    outb[off] = f2bf(v);
                } else {
                    outf[(size_t)row * N + col] = v;
                }
            }
}

// ---------------- MFMA flash causal attention, 128-key pairs ----------------
// grid (B*H, T/128), block 512 = 8 waves, wave w owns queries qb+16w..+15.
// Per pair step: stage K[128][d] + V^T[d][128] (2 int4/thread each), one
// barrier-pair, then process the two 64-key halves back-to-back. S^T = K Q^T
// (lane owns one query q=lm: scalar mi/li, 4-shfl reductions, b64 P stores).
// Wave-uniform skip of fully-masked halves at the diagonal.
__global__ __launch_bounds__(512) void attn_mfma(const unsigned short* __restrict__ qkvb,
                                                 const float* __restrict__ table,
                                                 unsigned short* __restrict__ y) {
    const int bh = blockIdx.x, b = bh >> 4, h = bh & 15;
    const int qb = (7 - blockIdx.y) * 128;  // longest blocks first
    const int tid = threadIdx.x, lane = tid & 63, wave = tid >> 6;
    const int quad = lane >> 4, lm = lane & 15;

    __shared__ __attribute__((aligned(16))) unsigned short Ks[128][72];     // [j][d]
    __shared__ __attribute__((aligned(16))) unsigned short Vs[64][136];     // [d][j] (V^T)
    __shared__ __attribute__((aligned(16))) unsigned short Ps[8][16][72];   // [wave][q][j]
    __shared__ float tb[1280];

    const unsigned short* Qg  = qkvb + ((size_t)(b)*16 + h) * 65536;       // [t][d]
    const unsigned short* Kg  = qkvb + ((size_t)(4 + b)*16 + h) * 65536;   // [t][d]
    const unsigned short* Vtg = qkvb + ((size_t)(8 + b)*16 + h) * 65536;   // [d][t]

    const bf16x8 qf0 = *(const bf16x8*)(Qg + (size_t)(qb + wave * 16 + lm) * 64 + quad * 8);
    const bf16x8 qf1 = *(const bf16x8*)(Qg + (size_t)(qb + wave * 16 + lm) * 64 + 32 + quad * 8);

    const int tbn = qb + 255;
    for (int i = tid; i < tbn; i += 512) tb[i] = table[(896 + i) * 16 + h];

    f32x4 oacc[4];
#pragma unroll
    for (int nb = 0; nb < 4; ++nb) oacc[nb] = (f32x4){0.f, 0.f, 0.f, 0.f};
    float mi = -1e30f, li = 0.f;  // per-lane: one query q = qb + wave*16 + lm

    // staging addresses: K 2 int4/thread, V^T 2 int4/thread
    const int kr = tid >> 2, kc = (tid & 3) * 16;   // Ks[kr][kc], [kr][kc+8]
    const int vr = tid >> 3, vc = (tid & 7) * 8;    // Vs[vr][vc], [vr][vc+64]
    int4 pk0 = *(const int4*)(Kg + (size_t)kr * 64 + kc);
    int4 pk1 = *(const int4*)(Kg + (size_t)kr * 64 + kc + 8);
    int4 pv0 = *(const int4*)(Vtg + (size_t)vr * 1024 + vc);
    int4 pv1 = *(const int4*)(Vtg + (size_t)vr * 1024 + vc + 64);

    const int q = qb + wave * 16 + lm;
    const int qwave_hi = qb + wave * 16 + 15;
    const int ktpairs = qb / 128 + 1;
    for (int kt2 = 0; kt2 < ktpairs; ++kt2) {
        *(int4*)&Ks[kr][kc]     = pk0;
        *(int4*)&Ks[kr][kc + 8] = pk1;
        *(int4*)&Vs[vr][vc]      = pv0;
        *(int4*)&Vs[vr][vc + 64] = pv1;
        __syncthreads();
        if (kt2 + 1 < ktpairs) {
            const int j0n = (kt2 + 1) * 128;
            pk0 = *(const int4*)(Kg + (size_t)(j0n + kr) * 64 + kc);
            pk1 = *(const int4*)(Kg + (size_t)(j0n + kr) * 64 + kc + 8);
            pv0 = *(const int4*)(Vtg + (size_t)vr * 1024 + j0n + vc);
            pv1 = *(const int4*)(Vtg + (size_t)vr * 1024 + j0n + vc + 64);
        }

#pragma unroll
        for (int hf = 0; hf < 2; ++hf) {
            const int jb = kt2 * 128 + hf * 64;
            if (qwave_hi < jb) continue;  // wave-uniform: fully masked half

            // S^T = K Q^T : A = K rows (j), B = Q rows (q)
            f32x4 s[4];
#pragma unroll
            for (int nb = 0; nb < 4; ++nb) {
                bf16x8 k0 = *(const bf16x8*)(&Ks[hf * 64 + nb * 16 + lm][quad * 8]);
                bf16x8 k1 = *(const bf16x8*)(&Ks[hf * 64 + nb * 16 + lm][32 + quad * 8]);
                s[nb] = (f32x4){0.f, 0.f, 0.f, 0.f};
                s[nb] = __builtin_amdgcn_mfma_f32_16x16x32_bf16(k0, qf0, s[nb], 0, 0, 0);
                s[nb] = __builtin_amdgcn_mfma_f32_16x16x32_bf16(k1, qf1, s[nb], 0, 0, 0);
            }

            // scale + rel-pos bias + causal mask (q lane-constant)
            const int jq0 = jb + quad * 4;
#pragma unroll
            for (int nb = 0; nb < 4; ++nb)
#pragma unroll
                for (int i = 0; i < 4; ++i) {
                    const int j = jq0 + nb * 16 + i;
                    const float v = fmaf(s[nb][i], 0.125f, tb[q - j + 127]);
                    s[nb][i] = (j <= q) ? v : -1e30f;
                }

            // online softmax (scalar state; cross-quad shuffles only)
            float mx = -1e30f;
#pragma unroll
            for (int nb = 0; nb < 4; ++nb)
#pragma unroll
                for (int i = 0; i < 4; ++i) mx = fmaxf(mx, s[nb][i]);
            mx = fmaxf(mx, __shfl_xor(mx, 16, 64));
            mx = fmaxf(mx, __shfl_xor(mx, 32, 64));
            const float mnew = fmaxf(mi, mx);
            const float alpha = __expf(mi - mnew);
            mi = mnew;
#pragma unroll
            for (int nb = 0; nb < 4; ++nb)
#pragma unroll
                for (int i = 0; i < 4; ++i) s[nb][i] = __expf(s[nb][i] - mnew);
            float ps = 0.f;
#pragma unroll
            for (int nb = 0; nb < 4; ++nb)
                ps += (s[nb][0] + s[nb][1]) + (s[nb][2] + s[nb][3]);
            ps += __shfl_xor(ps, 16, 64);
            ps += __shfl_xor(ps, 32, 64);
            li = li * alpha + ps;

            // P store: [wave][q=lm][j local], 4 consecutive j -> b64
#pragma unroll
            for (int nb = 0; nb < 4; ++nb) {
                union { unsigned short u[4]; int2 v; } p4;
                p4.u[0] = f2bf(s[nb][0]);
                p4.u[1] = f2bf(s[nb][1]);
                p4.u[2] = f2bf(s[nb][2]);
                p4.u[3] = f2bf(s[nb][3]);
                *(int2*)(&Ps[wave][lm][nb * 16 + quad * 4]) = p4.v;
            }

            // broadcast alpha (at lane q=lm) to C-layout rows (q=quad*4+i)
            float alr[4];
#pragma unroll
            for (int i = 0; i < 4; ++i) alr[i] = __shfl(alpha, quad * 4 + i, 64);
#pragma unroll
            for (int nb = 0; nb < 4; ++nb)
#pragma unroll
                for (int i = 0; i < 4; ++i) oacc[nb][i] *= alr[i];

            // O += P V : A = P [q][j] (b128), B = V^T [d][j] (b128)
            const bf16x8 p0 = *(const bf16x8*)(&Ps[wave][lm][quad * 8]);
            const bf16x8 p1 = *(const bf16x8*)(&Ps[wave][lm][32 + quad * 8]);
#pragma unroll
            for (int nb = 0; nb < 4; ++nb) {
                bf16x8 v0 = *(const bf16x8*)(&Vs[nb * 16 + lm][hf * 64 + quad * 8]);
                bf16x8 v1 = *(const bf16x8*)(&Vs[nb * 16 + lm][hf * 64 + 32 + quad * 8]);
                oacc[nb] = __builtin_amdgcn_mfma_f32_16x16x32_bf16(p0, v0, oacc[nb], 0, 0, 0);
                oacc[nb] = __builtin_amdgcn_mfma_f32_16x16x32_bf16(p1, v1, oacc[nb], 0, 0, 0);
            }
        }
        __syncthreads();
    }

    // epilogue: O / li -> y (B,T,C) bf16 (oacc row = q local quad*4+i, col = d)
    const float linv = 1.0f / li;
    float invr[4];
#pragma unroll
    for (int i = 0; i < 4; ++i) invr[i] = __shfl(linv, quad * 4 + i, 64);
#pragma unroll
    for (int nb = 0; nb < 4; ++nb)
#pragma unroll
        for (int i = 0; i < 4; ++i) {
            const int qq = qb + wave * 16 + quad * 4 + i;
            const int d = nb * 16 + lm;
            y[((size_t)(b * 1024 + qq)) * 1024 + h * 64 + d] = f2bf(oacc[nb][i] * invr[i]);
        }
}

extern "C" void kernel_launch(void* const* d_in, const int* in_sizes, int n_in,
                              void* d_out, int out_size, void* d_ws, size_t ws_size,
                              hipStream_t stream) {
    const float* x      = (const float*)d_in[0];
    const float* qkv_w  = (const float*)d_in[1];
    const float* qkv_b  = (const float*)d_in[2];
    const float* proj_w = (const float*)d_in[3];
    const float* proj_b = (const float*)d_in[4];
    const float* rel    = (const float*)d_in[5];
    float* out = (float*)d_out;

    char* ws = (char*)d_ws;
    float* table         = (float*)(ws + 16777216);
    unsigned short* qkvb = (unsigned short*)(ws + 16908288);
    unsigned short* yb   = (unsigned short*)(ws + 42074112);

    // y==24 row of blocks does table_reduce duty
    gemm_bt<0, true><<<dim3(32, 25), 512, 0, stream>>>(x, qkv_w, qkv_b, qkvb, nullptr,
                                                       rel, table, 4096, 3072, 1024);
    attn_mfma<<<dim3(64, 8), 512, 0, stream>>>(qkvb, table, yb);
    gemm_bt<1, false><<<dim3(32, 8), 512, 0, stream>>>(yb, proj_w, proj_b, nullptr, out,
                                                       nullptr, nullptr, 4096, 1024, 1024);
}